// Round 1
// baseline (471.329 us; speedup 1.0000x reference)
//
#include <hip/hip_runtime.h>
#include <math.h>

#define TOK_PER_BLK 64
#define THREADS     512
#define E_PER_WAVE  8
#define DCHUNK      64
#define DIM         2048
#define NEXP        64
#define NTOK        16384

__global__ __launch_bounds__(THREADS)
void moirai_gating_kernel(const float* __restrict__ x,
                          const float* __restrict__ W,
                          const float* __restrict__ bias,
                          float* __restrict__ out)
{
    // smem dual-purpose: [0..4095] x-tile (64 tok x 64 d, XOR-swizzled float4),
    // then reused as logits [64 tok][65] (stride 65 => conflict-free scan).
    __shared__ float smem[TOK_PER_BLK * 65];

    const int tid  = threadIdx.x;          // 0..511
    const int lane = tid & 63;             // token within block
    const int wave = tid >> 6;             // 0..7
    const int e0   = __builtin_amdgcn_readfirstlane(wave * E_PER_WAVE);
    const int tok0 = blockIdx.x * TOK_PER_BLK;

    // fp64 master accumulators (chunk partials in fp32) to keep logit error
    // ~3e-7 so top-k indices match the numpy reference.
    double accd[E_PER_WAVE];
#pragma unroll
    for (int e = 0; e < E_PER_WAVE; e++) accd[e] = 0.0;

    for (int dc = 0; dc < DIM; dc += DCHUNK) {
        __syncthreads();
        // ---- stage x tile: 64 tokens x 64 floats, float4-granular XOR swizzle
#pragma unroll
        for (int r = 0; r < 2; r++) {
            const int q = tid + r * THREADS;   // 0..1023 float4 slots
            const int t = q >> 4;              // token row 0..63
            const int c = q & 15;              // float4 column 0..15
            const float4 v = *(const float4*)(x + (size_t)(tok0 + t) * DIM + dc + 4 * c);
            const int cs = c ^ (t & 15);
            *(float4*)(smem + t * DCHUNK + 4 * cs) = v;
        }
        __syncthreads();

        // ---- each lane pulls its token's 64 values into registers (ds_read_b128)
        float xv[DCHUNK];
#pragma unroll
        for (int c = 0; c < 16; c++) {
            const int cs = c ^ (lane & 15);
            const float4 v = *(const float4*)(smem + lane * DCHUNK + 4 * cs);
            xv[4 * c + 0] = v.x; xv[4 * c + 1] = v.y;
            xv[4 * c + 2] = v.z; xv[4 * c + 3] = v.w;
        }

        // ---- 8 experts x 64 d FMAs; W at wave-uniform addresses -> s_load
#pragma unroll
        for (int e = 0; e < E_PER_WAVE; e++) {
            const float* wrow = W + (size_t)(e0 + e) * DIM + dc;
            float p = 0.f;
#pragma unroll
            for (int c = 0; c < 16; c++) {
                const float4 wv = *(const float4*)(wrow + 4 * c);
                p = fmaf(xv[4 * c + 0], wv.x, p);
                p = fmaf(xv[4 * c + 1], wv.y, p);
                p = fmaf(xv[4 * c + 2], wv.z, p);
                p = fmaf(xv[4 * c + 3], wv.w, p);
            }
            accd[e] += (double)p;
        }
    }

    __syncthreads();   // done reading x-tile region; reuse smem for logits
#pragma unroll
    for (int e = 0; e < E_PER_WAVE; e++) {
        smem[lane * 65 + e0 + e] = (float)accd[e] + bias[e0 + e];
    }
    __syncthreads();

    // ---- top-2 + softmax: one thread per token (wave 0 only)
    if (tid < TOK_PER_BLK) {
        const int t = tid;
        float v0 = -INFINITY, v1 = -INFINITY;
        int   i0 = 0, i1 = 0;
        for (int e = 0; e < NEXP; e++) {
            const float v = smem[t * 65 + e];   // (t+e)%32 banks: conflict-free
            if (v > v0) { v1 = v0; i1 = i0; v0 = v; i0 = e; }
            else if (v > v1) { v1 = v; i1 = e; }
        }
        const float e1 = expf(v1 - v0);   // v1 <= v0, stable
        const float s  = 1.f + e1;
        const int   g  = tok0 + t;
        out[2 * g + 0] = 1.f / s;
        out[2 * g + 1] = e1 / s;
        out[2 * NTOK + 2 * g + 0] = (float)i0;
        out[2 * NTOK + 2 * g + 1] = (float)i1;
    }
}

extern "C" void kernel_launch(void* const* d_in, const int* in_sizes, int n_in,
                              void* d_out, int out_size, void* d_ws, size_t ws_size,
                              hipStream_t stream) {
    const float* x    = (const float*)d_in[0];
    const float* W    = (const float*)d_in[1];
    const float* bias = (const float*)d_in[2];
    float*       out  = (float*)d_out;

    hipLaunchKernelGGL(moirai_gating_kernel,
                       dim3(NTOK / TOK_PER_BLK), dim3(THREADS), 0, stream,
                       x, W, bias, out);
}

// Round 2
// 308.000 us; speedup vs baseline: 1.5303x; 1.5303x over previous
//
#include <hip/hip_runtime.h>
#include <math.h>

#define TOK_PER_BLK 64
#define THREADS     1024      // 16 waves
#define E_PER_WAVE  4         // 16 waves x 4 experts = 64
#define DCHUNK      64
#define DIM         2048
#define NCHUNK      (DIM / DCHUNK)   // 32
#define NEXP        64
#define NTOK        16384

__global__ __launch_bounds__(THREADS, 4)
void moirai_gating_kernel(const float* __restrict__ x,
                          const float* __restrict__ W,
                          const float* __restrict__ bias,
                          float* __restrict__ out)
{
    // Double-buffered x tile: 2 x (64 tok x 16 float4), XOR-swizzled columns.
    __shared__ float4 sx[2][TOK_PER_BLK * 16];
    __shared__ float  slog[TOK_PER_BLK * 65];   // logits, stride 65 (conflict-free)

    const int tid  = threadIdx.x;
    const int lane = tid & 63;                          // token within block
    // wave id made provably uniform so W address scalarizes to s_load:
    const int e0   = __builtin_amdgcn_readfirstlane((int)(tid >> 6)) * E_PER_WAVE;
    const int tok0 = blockIdx.x * TOK_PER_BLK;

    // Staging role: each thread owns one float4 of the 64x64 tile.
    const int st = tid >> 4;            // row 0..63
    const int sc = tid & 15;            // float4 col 0..15
    const int sslot = st * 16 + (sc ^ (st & 15));       // swizzled LDS slot
    const float* gsrc = x + (size_t)(tok0 + st) * DIM + 4 * sc;

    double accd[E_PER_WAVE];
#pragma unroll
    for (int e = 0; e < E_PER_WAVE; e++) accd[e] = 0.0;

    // ---- prologue: stage chunk 0
    sx[0][sslot] = *(const float4*)(gsrc);
    __syncthreads();

    for (int k = 0; k < NCHUNK; ++k) {
        // issue next chunk's global load early (overlaps with compute)
        float4 nv;
        if (k < NCHUNK - 1) nv = *(const float4*)(gsrc + (k + 1) * DCHUNK);

        const float4* tile = sx[k & 1];
        const float*  wch  = W + (size_t)e0 * DIM + k * DCHUNK;

        float p[E_PER_WAVE] = {0.f, 0.f, 0.f, 0.f};
        // j-outer / e-inner: live x-state is ONE float4; each LDS word read once.
#pragma unroll
        for (int j = 0; j < 16; ++j) {
            const float4 xv = tile[lane * 16 + (j ^ (lane & 15))];  // logical col j
#pragma unroll
            for (int e = 0; e < E_PER_WAVE; ++e) {
                const float4 wv = *(const float4*)(wch + (size_t)e * DIM + 4 * j);
                p[e] = fmaf(xv.x, wv.x, p[e]);
                p[e] = fmaf(xv.y, wv.y, p[e]);
                p[e] = fmaf(xv.z, wv.z, p[e]);
                p[e] = fmaf(xv.w, wv.w, p[e]);
            }
        }
#pragma unroll
        for (int e = 0; e < E_PER_WAVE; ++e) accd[e] += (double)p[e];

        if (k < NCHUNK - 1) sx[(k + 1) & 1][sslot] = nv;
        __syncthreads();   // one barrier per chunk: publishes writes, fences reads
    }

    // ---- logits to LDS (stride 65: (lane + e)%32 banks, 2-way max = free)
#pragma unroll
    for (int e = 0; e < E_PER_WAVE; ++e)
        slog[lane * 65 + e0 + e] = (float)accd[e] + bias[e0 + e];
    __syncthreads();

    // ---- top-2 + softmax: one thread per token
    if (tid < TOK_PER_BLK) {
        const int t = tid;
        float v0 = -INFINITY, v1 = -INFINITY;
        int   i0 = 0, i1 = 0;
        for (int e = 0; e < NEXP; e++) {
            const float v = slog[t * 65 + e];
            if (v > v0) { v1 = v0; i1 = i0; v0 = v; i0 = e; }
            else if (v > v1) { v1 = v; i1 = e; }
        }
        const float e1 = expf(v1 - v0);   // v1 <= v0: stable
        const float s  = 1.f + e1;
        const int   g  = tok0 + t;
        out[2 * g + 0] = 1.f / s;
        out[2 * g + 1] = e1 / s;
        out[2 * NTOK + 2 * g + 0] = (float)i0;
        out[2 * NTOK + 2 * g + 1] = (float)i1;
    }
}

extern "C" void kernel_launch(void* const* d_in, const int* in_sizes, int n_in,
                              void* d_out, int out_size, void* d_ws, size_t ws_size,
                              hipStream_t stream) {
    const float* x    = (const float*)d_in[0];
    const float* W    = (const float*)d_in[1];
    const float* bias = (const float*)d_in[2];
    float*       out  = (float*)d_out;

    hipLaunchKernelGGL(moirai_gating_kernel,
                       dim3(NTOK / TOK_PER_BLK), dim3(THREADS), 0, stream,
                       x, W, bias, out);
}

// Round 3
// 226.288 us; speedup vs baseline: 2.0829x; 1.3611x over previous
//
#include <hip/hip_runtime.h>
#include <math.h>

typedef _Float16 half8 __attribute__((ext_vector_type(8)));
typedef float floatx4 __attribute__((ext_vector_type(4)));

#define NTOK 16384
#define DIM  2048
#define NEXP 64
#define MB   32                 // tokens per block
#define NBLK (NTOK / MB)        // 512 blocks
#define WSW_HALF8 (64 * 4 * 64) // per split: 64 ksteps x 4 ntiles x 64 lanes
#define WSW_BYTES (2 * WSW_HALF8 * 16)

// ---- prep: split W (fp32) into f16 hi + scaled-lo, pre-swizzled into
// B-fragment order: frag[sg][tg][lane] holds W[tg*16+(lane&15)][sg*32+(lane>>4)*8 + 0..7]
__global__ void wprep_kernel(const float* __restrict__ W, _Float16* __restrict__ wsw) {
    const int id   = blockIdx.x * blockDim.x + threadIdx.x; // 0..16383
    const int lane = id & 63;
    const int tg   = (id >> 6) & 3;
    const int sg   = id >> 8;                               // 0..63
    const int e    = tg * 16 + (lane & 15);
    const int k    = sg * 32 + (lane >> 4) * 8;
    const float* src = W + (size_t)e * DIM + k;
    half8 h, l;
#pragma unroll
    for (int j = 0; j < 8; j++) {
        const float v  = src[j];
        const _Float16 hh = (_Float16)v;
        h[j] = hh;
        l[j] = (_Float16)((v - (float)hh) * 2048.0f);   // scale 2^11: keeps lo normal-range
    }
    const size_t slot = (size_t)(sg * 4 + tg) * 64 + lane;
    ((half8*)wsw)[slot]             = h;
    ((half8*)wsw)[WSW_HALF8 + slot] = l;
}

// ---- main GEMM + top2 + softmax. No barriers in the K-loop.
template <bool USE_WS>
__global__ __launch_bounds__(512, 4)
void gating_mfma_kernel(const float* __restrict__ x, const float* __restrict__ W,
                        const _Float16* __restrict__ wsw, const float* __restrict__ bias,
                        float* __restrict__ out)
{
    __shared__ float part[2 * MB * 65];   // [khalf][token][expert], stride 65 = conflict-free

    const int tid  = threadIdx.x;
    const int lane = tid & 63;
    const int w    = tid >> 6;        // 0..7
    const int mt   = w & 1;           // m-tile (16 tokens)
    const int nh   = (w >> 1) & 1;    // n-half (32 experts)
    const int kh   = w >> 2;          // K-half (1024 dims)
    const int col  = lane & 15;
    const int quad = lane >> 4;
    const int tok0 = blockIdx.x * MB;

    // A-operand row for this lane: A[m=lane&15][k=quad*8+j]
    const float* xrow = x + (size_t)(tok0 + mt * 16 + col) * DIM + kh * 1024 + quad * 8;

    floatx4 a0m = {0,0,0,0}, a0l = {0,0,0,0};   // tile 0: experts nh*32+0..15
    floatx4 a1m = {0,0,0,0}, a1l = {0,0,0,0};   // tile 1: experts nh*32+16..31

    const half8* bhp = ((const half8*)wsw) + ((size_t)(kh * 32) * 4 + nh * 2) * 64 + lane;
    const half8* blp = bhp + WSW_HALF8;

#pragma unroll 2
    for (int s = 0; s < 32; ++s) {
        // ---- A: 8 fp32, split into f16 hi + scaled lo
        const float4 v0 = *(const float4*)(xrow + s * 32);
        const float4 v1 = *(const float4*)(xrow + s * 32 + 4);
        const float av[8] = {v0.x, v0.y, v0.z, v0.w, v1.x, v1.y, v1.z, v1.w};
        half8 ah, al;
#pragma unroll
        for (int j = 0; j < 8; j++) {
            const _Float16 hh = (_Float16)av[j];
            ah[j] = hh;
            al[j] = (_Float16)((av[j] - (float)hh) * 2048.0f);
        }
        // ---- B fragments
        half8 bh0, bh1, bl0, bl1;
        if constexpr (USE_WS) {
            bh0 = bhp[s * 256];        bh1 = bhp[s * 256 + 64];
            bl0 = blp[s * 256];        bl1 = blp[s * 256 + 64];
        } else {
            const int k = kh * 1024 + s * 32 + quad * 8;
#pragma unroll
            for (int t = 0; t < 2; t++) {
                const float* wr = W + (size_t)((nh * 2 + t) * 16 + col) * DIM + k;
                const float4 w0 = *(const float4*)(wr);
                const float4 w1 = *(const float4*)(wr + 4);
                const float wv[8] = {w0.x, w0.y, w0.z, w0.w, w1.x, w1.y, w1.z, w1.w};
                half8 h, l;
#pragma unroll
                for (int j = 0; j < 8; j++) {
                    const _Float16 hh = (_Float16)wv[j];
                    h[j] = hh;
                    l[j] = (_Float16)((wv[j] - (float)hh) * 2048.0f);
                }
                if (t == 0) { bh0 = h; bl0 = l; } else { bh1 = h; bl1 = l; }
            }
        }
        // ---- 3-term split product (lo terms carry 2^11 scale, folded out in epilogue)
        a0m = __builtin_amdgcn_mfma_f32_16x16x32_f16(ah, bh0, a0m, 0, 0, 0);
        a1m = __builtin_amdgcn_mfma_f32_16x16x32_f16(ah, bh1, a1m, 0, 0, 0);
        a0l = __builtin_amdgcn_mfma_f32_16x16x32_f16(ah, bl0, a0l, 0, 0, 0);
        a1l = __builtin_amdgcn_mfma_f32_16x16x32_f16(ah, bl1, a1l, 0, 0, 0);
        a0l = __builtin_amdgcn_mfma_f32_16x16x32_f16(al, bh0, a0l, 0, 0, 0);
        a1l = __builtin_amdgcn_mfma_f32_16x16x32_f16(al, bh1, a1l, 0, 0, 0);
    }

    // C/D layout: row(m) = quad*4 + r, col(n) = lane&15  [m89-verified]
    const float inv = 1.0f / 2048.0f;
#pragma unroll
    for (int r = 0; r < 4; r++) {
        const int m = mt * 16 + quad * 4 + r;
        part[(kh * MB + m) * 65 + nh * 32 + col]      = a0m[r] + a0l[r] * inv;
        part[(kh * MB + m) * 65 + nh * 32 + 16 + col] = a1m[r] + a1l[r] * inv;
    }
    __syncthreads();

    // ---- top-2 + softmax, one thread per token
    if (tid < MB) {
        const int t = tid;
        float v0 = -INFINITY, v1 = -INFINITY;
        int   i0 = 0, i1 = 0;
        for (int e = 0; e < NEXP; e++) {
            const float v = part[t * 65 + e] + part[(MB + t) * 65 + e] + bias[e];
            if (v > v0) { v1 = v0; i1 = i0; v0 = v; i0 = e; }
            else if (v > v1) { v1 = v; i1 = e; }
        }
        const float e1 = expf(v1 - v0);   // v1 <= v0: stable
        const float s  = 1.f + e1;
        const int   g  = tok0 + t;
        out[2 * g + 0] = 1.f / s;
        out[2 * g + 1] = e1 / s;
        out[2 * NTOK + 2 * g + 0] = (float)i0;
        out[2 * NTOK + 2 * g + 1] = (float)i1;
    }
}

extern "C" void kernel_launch(void* const* d_in, const int* in_sizes, int n_in,
                              void* d_out, int out_size, void* d_ws, size_t ws_size,
                              hipStream_t stream) {
    const float* x    = (const float*)d_in[0];
    const float* W    = (const float*)d_in[1];
    const float* bias = (const float*)d_in[2];
    float*       out  = (float*)d_out;
    _Float16*    wsw  = (_Float16*)d_ws;

    if (ws_size >= (size_t)WSW_BYTES) {
        hipLaunchKernelGGL(wprep_kernel, dim3(64), dim3(256), 0, stream, (const float*)d_in[1], wsw);
        hipLaunchKernelGGL((gating_mfma_kernel<true>), dim3(NBLK), dim3(512), 0, stream,
                           x, W, wsw, bias, out);
    } else {
        hipLaunchKernelGGL((gating_mfma_kernel<false>), dim3(NBLK), dim3(512), 0, stream,
                           x, W, wsw, bias, out);
    }
}

// Round 4
// 219.886 us; speedup vs baseline: 2.1435x; 1.0291x over previous
//
#include <hip/hip_runtime.h>
#include <math.h>

typedef _Float16 half8 __attribute__((ext_vector_type(8)));
typedef float floatx4 __attribute__((ext_vector_type(4)));

#define NTOK  16384
#define DIM   2048
#define NEXP  64
#define MB    16                  // tokens per block
#define NBLK  (NTOK / MB)         // 1024 blocks
#define NSTEP 16                  // K-steps per wave: K/4 = 512 = 16*32
#define WSW_HALF8 (64 * 4 * 64)   // per split: 64 ksteps x 4 ntiles x 64 lanes
#define WSW_BYTES (2 * WSW_HALF8 * 16)

// ---- prep: split W (fp32) into f16 hi + scaled-lo (2^11), B-fragment order:
// slot(sg,tg,lane) = (sg*4+tg)*64+lane holds W[tg*16+(lane&15)][sg*32+(lane>>4)*8 + 0..7]
__global__ void wprep_kernel(const float* __restrict__ W, _Float16* __restrict__ wsw) {
    const int id   = blockIdx.x * blockDim.x + threadIdx.x; // 0..16383
    const int lane = id & 63;
    const int tg   = (id >> 6) & 3;
    const int sg   = id >> 8;                               // 0..63
    const int e    = tg * 16 + (lane & 15);
    const int k    = sg * 32 + (lane >> 4) * 8;
    const float* src = W + (size_t)e * DIM + k;
    half8 h, l;
#pragma unroll
    for (int j = 0; j < 8; j++) {
        const float v  = src[j];
        const _Float16 hh = (_Float16)v;
        h[j] = hh;
        l[j] = (_Float16)((v - (float)hh) * 2048.0f);
    }
    const size_t slot = (size_t)(sg * 4 + tg) * 64 + lane;
    ((half8*)wsw)[slot]             = h;
    ((half8*)wsw)[WSW_HALF8 + slot] = l;
}

__device__ __forceinline__ void split_a(const float4& v0, const float4& v1,
                                        half8& hi, half8& lo) {
    const float av[8] = {v0.x, v0.y, v0.z, v0.w, v1.x, v1.y, v1.z, v1.w};
#pragma unroll
    for (int j = 0; j < 8; j++) {
        const _Float16 hh = (_Float16)av[j];
        hi[j] = hh;
        lo[j] = (_Float16)((av[j] - (float)hh) * 2048.0f);
    }
}

template <bool USE_WS>
__global__ __launch_bounds__(256, 4)
void gating_mfma_kernel(const float* __restrict__ x, const float* __restrict__ W,
                        const _Float16* __restrict__ wsw, const float* __restrict__ bias,
                        float* __restrict__ out)
{
    __shared__ float part[4 * MB * 65];   // [kquarter][token][expert], stride 65

    const int tid  = threadIdx.x;
    const int lane = tid & 63;
    const int kh   = tid >> 6;          // 0..3: K-quarter (512 dims, 16 steps)
    const int col  = lane & 15;
    const int quad = lane >> 4;
    const int tok0 = blockIdx.x * MB;

    // A: lane holds A[m=col][k=quad*8 + 0..7] of token tok0+col
    const float* xrow = x + (size_t)(tok0 + col) * DIM + kh * 512 + quad * 8;
    // B fragments for this K-quarter: step s, tile tg at bh_base[s*256 + tg*64]
    const half8* bh_base = (const half8*)wsw + (size_t)kh * 4096 + lane;
    const half8* bl_base = bh_base + WSW_HALF8;

    floatx4 accm[4] = {{0,0,0,0},{0,0,0,0},{0,0,0,0},{0,0,0,0}};
    floatx4 accl[4] = {{0,0,0,0},{0,0,0,0},{0,0,0,0},{0,0,0,0}};

    // ---- explicit pipeline: x depth-2, B depth-1
    float4 xf[2][2];
    half8  bhf[2][4], blf[2][4];

    xf[0][0] = *(const float4*)(xrow);
    xf[0][1] = *(const float4*)(xrow + 4);
    xf[1][0] = *(const float4*)(xrow + 32);
    xf[1][1] = *(const float4*)(xrow + 36);
    if constexpr (USE_WS) {
#pragma unroll
        for (int tg = 0; tg < 4; tg++) { bhf[0][tg] = bh_base[tg * 64]; blf[0][tg] = bl_base[tg * 64]; }
    } else {
#pragma unroll
        for (int tg = 0; tg < 4; tg++) {
            const float* wr = W + (size_t)(tg * 16 + col) * DIM + kh * 512 + quad * 8;
            split_a(*(const float4*)(wr), *(const float4*)(wr + 4), bhf[0][tg], blf[0][tg]);
        }
    }

#pragma unroll
    for (int s = 0; s < NSTEP; ++s) {
        const int cur = s & 1, nxt = cur ^ 1;

        // consume current x into split fragments (frees xf[cur])
        half8 ah, alo;
        split_a(xf[cur][0], xf[cur][1], ah, alo);

        // prefetch x(s+2) into the slot just freed
        if (s + 2 < NSTEP) {
            xf[cur][0] = *(const float4*)(xrow + (s + 2) * 32);
            xf[cur][1] = *(const float4*)(xrow + (s + 2) * 32 + 4);
        }
        // prefetch B(s+1)
        if (s + 1 < NSTEP) {
            if constexpr (USE_WS) {
#pragma unroll
                for (int tg = 0; tg < 4; tg++) {
                    bhf[nxt][tg] = bh_base[(s + 1) * 256 + tg * 64];
                    blf[nxt][tg] = bl_base[(s + 1) * 256 + tg * 64];
                }
            } else {
#pragma unroll
                for (int tg = 0; tg < 4; tg++) {
                    const float* wr = W + (size_t)(tg * 16 + col) * DIM + kh * 512 + (s + 1) * 32 + quad * 8;
                    split_a(*(const float4*)(wr), *(const float4*)(wr + 4), bhf[nxt][tg], blf[nxt][tg]);
                }
            }
        }

        // 12 MFMAs: 4 n-tiles x (hi·hi, hi·lo, lo·hi)
#pragma unroll
        for (int tg = 0; tg < 4; tg++) {
            accm[tg] = __builtin_amdgcn_mfma_f32_16x16x32_f16(ah,  bhf[cur][tg], accm[tg], 0, 0, 0);
            accl[tg] = __builtin_amdgcn_mfma_f32_16x16x32_f16(ah,  blf[cur][tg], accl[tg], 0, 0, 0);
            accl[tg] = __builtin_amdgcn_mfma_f32_16x16x32_f16(alo, bhf[cur][tg], accl[tg], 0, 0, 0);
        }
    }

    // C/D layout: row(m)=quad*4+r, col(n)=lane&15  [m89-verified]
    const float inv = 1.0f / 2048.0f;
#pragma unroll
    for (int tg = 0; tg < 4; tg++) {
#pragma unroll
        for (int r = 0; r < 4; r++) {
            const int m = quad * 4 + r;
            part[(kh * MB + m) * 65 + tg * 16 + col] = accm[tg][r] + accl[tg][r] * inv;
        }
    }
    __syncthreads();

    // ---- top-2 + softmax: one thread per token
    if (tid < MB) {
        const int t = tid;
        float v0 = -INFINITY, v1 = -INFINITY;
        int   i0 = 0, i1 = 0;
        for (int e = 0; e < NEXP; e++) {
            const float v = part[t * 65 + e] + part[(MB + t) * 65 + e]
                          + part[(2 * MB + t) * 65 + e] + part[(3 * MB + t) * 65 + e]
                          + bias[e];
            if (v > v0) { v1 = v0; i1 = i0; v0 = v; i0 = e; }
            else if (v > v1) { v1 = v; i1 = e; }
        }
        const float e1 = expf(v1 - v0);   // v1 <= v0: stable
        const float sden = 1.f + e1;
        const int   g  = tok0 + t;
        out[2 * g + 0] = 1.f / sden;
        out[2 * g + 1] = e1 / sden;
        out[2 * NTOK + 2 * g + 0] = (float)i0;
        out[2 * NTOK + 2 * g + 1] = (float)i1;
    }
}

extern "C" void kernel_launch(void* const* d_in, const int* in_sizes, int n_in,
                              void* d_out, int out_size, void* d_ws, size_t ws_size,
                              hipStream_t stream) {
    const float* x    = (const float*)d_in[0];
    const float* W    = (const float*)d_in[1];
    const float* bias = (const float*)d_in[2];
    float*       out  = (float*)d_out;
    _Float16*    wsw  = (_Float16*)d_ws;

    if (ws_size >= (size_t)WSW_BYTES) {
        hipLaunchKernelGGL(wprep_kernel, dim3(64), dim3(256), 0, stream, (const float*)d_in[1], wsw);
        hipLaunchKernelGGL((gating_mfma_kernel<true>), dim3(NBLK), dim3(256), 0, stream,
                           x, W, wsw, bias, out);
    } else {
        hipLaunchKernelGGL((gating_mfma_kernel<false>), dim3(NBLK), dim3(256), 0, stream,
                           x, W, wsw, bias, out);
    }
}

// Round 5
// 208.076 us; speedup vs baseline: 2.2652x; 1.0568x over previous
//
#include <hip/hip_runtime.h>
#include <math.h>
#include <stdint.h>

typedef _Float16 half8 __attribute__((ext_vector_type(8)));
typedef float floatx4 __attribute__((ext_vector_type(4)));

#define NTOK   16384
#define DIM    2048
#define NEXP   64
#define MB     32                  // tokens per block
#define NBLK   (NTOK / MB)         // 512 blocks
#define KC     64                  // K per chunk
#define NCHUNK (DIM / KC)          // 32
#define WSW_H8 16384               // half8 slots per split (64 ksteps x 4 tg x 64 lanes)
#define WSW_BYTES (2 * WSW_H8 * 16)

#define A_BYTES 8192               // per buffer: 32 rows x 256 B
#define B_BYTES 16384              // per buffer: 2 splits x 8 KB
#define AOFF(b) ((b) * A_BYTES)
#define BOFF(b) (2 * A_BYTES + (b) * B_BYTES)
#define SMEM_BYTES (2 * A_BYTES + 2 * B_BYTES)   // 49152

// ---- prep: split W (fp32) into f16 hi + scaled-lo (2^11), B-fragment order:
// slot(sg,tg,lane) = (sg*4+tg)*64+lane holds W[tg*16+(lane&15)][sg*32+(lane>>4)*8 + 0..7]
__global__ void wprep_kernel(const float* __restrict__ W, _Float16* __restrict__ wsw) {
    const int id   = blockIdx.x * blockDim.x + threadIdx.x; // 0..16383
    const int lane = id & 63;
    const int tg   = (id >> 6) & 3;
    const int sg   = id >> 8;                               // 0..63
    const int e    = tg * 16 + (lane & 15);
    const int k    = sg * 32 + (lane >> 4) * 8;
    const float* src = W + (size_t)e * DIM + k;
    half8 h, l;
#pragma unroll
    for (int j = 0; j < 8; j++) {
        const float v  = src[j];
        const _Float16 hh = (_Float16)v;
        h[j] = hh;
        l[j] = (_Float16)((v - (float)hh) * 2048.0f);
    }
    const size_t slot = (size_t)(sg * 4 + tg) * 64 + lane;
    ((half8*)wsw)[slot]          = h;
    ((half8*)wsw)[WSW_H8 + slot] = l;
}

__device__ __forceinline__ void split_a(const float4& v0, const float4& v1,
                                        half8& hi, half8& lo) {
    const float av[8] = {v0.x, v0.y, v0.z, v0.w, v1.x, v1.y, v1.z, v1.w};
#pragma unroll
    for (int j = 0; j < 8; j++) {
        const _Float16 hh = (_Float16)av[j];
        hi[j] = hh;
        lo[j] = (_Float16)((av[j] - (float)hh) * 2048.0f);
    }
}

// async global->LDS DMA, 16 B/lane. LDS dest = uniform base + lane*16 (HW rule).
__device__ __forceinline__ void dma16(const void* g, const char* l) {
    __builtin_amdgcn_global_load_lds(
        (const __attribute__((address_space(1))) unsigned int*)(uintptr_t)g,
        (__attribute__((address_space(3))) unsigned int*)(uintptr_t)l,
        16, 0, 0);
}

template <bool USE_WS>
__global__ __launch_bounds__(256, 3)
void gating_lds_kernel(const float* __restrict__ x, const float* __restrict__ W,
                       const _Float16* __restrict__ wsw, const float* __restrict__ bias,
                       float* __restrict__ out)
{
    __shared__ char smem[SMEM_BYTES];

    const int tid  = threadIdx.x;
    const int lane = tid & 63;
    const int w    = tid >> 6;          // 0..3
    const int mt   = w & 1;             // m-tile (16 tokens)
    const int nh   = w >> 1;            // n-half (2 expert tiles)
    const int col  = lane & 15;
    const int quad = lane >> 4;
    const int tok0 = blockIdx.x * MB;
    const int m    = mt * 16 + col;     // this lane's token row (0..31)

    // ---- A DMA sources: issue a = w*2+i covers rows a*4..a*4+3 (256 B each).
    // Gather-side XOR swizzle within 128 B: LDS slot pz holds global piece
    // (pz&8)|((pz&7)^(row&7))  => frag ds_reads land on distinct banks.
    const float* gA[2];
    unsigned     lA[2];
#pragma unroll
    for (int i = 0; i < 2; i++) {
        const int a   = w * 2 + i;
        const int row = a * 4 + (lane >> 4);
        const int pz  = lane & 15;
        const int gp  = (pz & 8) | ((pz & 7) ^ (row & 7));
        gA[i] = x + (size_t)(tok0 + row) * DIM + gp * 4;
        lA[i] = (unsigned)(a * 1024);
    }
    // ---- B DMA sources: contiguous copy of wsw chunk (lane-contiguous LDS).
    const half8* gB[4];
    unsigned     lB[4];
    if constexpr (USE_WS) {
#pragma unroll
        for (int j = 0; j < 4; j++) {
            const int b = w * 4 + j;
            const int split = b >> 3, idx = b & 7;
            gB[j] = (const half8*)wsw + (size_t)split * WSW_H8 + idx * 64 + lane;
            lB[j] = (unsigned)(split * 8192 + idx * 1024);
        }
    }

    floatx4 accm[2] = {{0,0,0,0},{0,0,0,0}};
    floatx4 accl[2] = {{0,0,0,0},{0,0,0,0}};

    // prologue: DMA chunk 0 into buffer 0
#pragma unroll
    for (int i = 0; i < 2; i++) dma16(gA[i], smem + AOFF(0) + lA[i]);
    if constexpr (USE_WS) {
#pragma unroll
        for (int j = 0; j < 4; j++) dma16(gB[j], smem + BOFF(0) + lB[j]);
    }

#pragma unroll 2
    for (int c = 0; c < NCHUNK; ++c) {
        __syncthreads();    // compiler emits vmcnt(0): chunk c staged for all waves
        if (c + 1 < NCHUNK) {
            const int nb = (c + 1) & 1;
#pragma unroll
            for (int i = 0; i < 2; i++)
                dma16(gA[i] + (size_t)(c + 1) * KC, smem + AOFF(nb) + lA[i]);
            if constexpr (USE_WS) {
#pragma unroll
                for (int j = 0; j < 4; j++)
                    dma16(gB[j] + (size_t)(c + 1) * 512, smem + BOFF(nb) + lB[j]);
            }
        }
        const char* Ab = smem + AOFF(c & 1);
        const char* Bb = smem + BOFF(c & 1);
#pragma unroll
        for (int s = 0; s < 2; s++) {
            const float4 v0 = *(const float4*)(Ab + m * 256 + (8 * s + ((2 * quad + 0) ^ (m & 7))) * 16);
            const float4 v1 = *(const float4*)(Ab + m * 256 + (8 * s + ((2 * quad + 1) ^ (m & 7))) * 16);
            half8 ah, alo;
            split_a(v0, v1, ah, alo);
#pragma unroll
            for (int t = 0; t < 2; t++) {
                const int tg = nh * 2 + t;
                half8 bh, bl;
                if constexpr (USE_WS) {
                    bh = *(const half8*)(Bb + (s * 4 + tg) * 1024 + lane * 16);
                    bl = *(const half8*)(Bb + 8192 + (s * 4 + tg) * 1024 + lane * 16);
                } else {
                    const float* wr = W + (size_t)(tg * 16 + col) * DIM + c * KC + s * 32 + quad * 8;
                    split_a(*(const float4*)wr, *(const float4*)(wr + 4), bh, bl);
                }
                accm[t] = __builtin_amdgcn_mfma_f32_16x16x32_f16(ah,  bh, accm[t], 0, 0, 0);
                accl[t] = __builtin_amdgcn_mfma_f32_16x16x32_f16(ah,  bl, accl[t], 0, 0, 0);
                accl[t] = __builtin_amdgcn_mfma_f32_16x16x32_f16(alo, bh, accl[t], 0, 0, 0);
            }
        }
    }

    __syncthreads();            // all staging reads done; alias logits onto A region
    float* lg = (float*)smem;   // [32 tok][65] stride-65
    const float inv = 1.0f / 2048.0f;
#pragma unroll
    for (int t = 0; t < 2; t++) {
        const int tg = nh * 2 + t;
#pragma unroll
        for (int r = 0; r < 4; r++) {
            // C/D: row = quad*4+r, col = lane&15  [m89-verified]
            lg[(mt * 16 + quad * 4 + r) * 65 + tg * 16 + col] = accm[t][r] + accl[t][r] * inv;
        }
    }
    __syncthreads();

    if (tid < MB) {
        const int t = tid;
        float v0 = -INFINITY, v1 = -INFINITY;
        int   i0 = 0, i1 = 0;
        for (int e = 0; e < NEXP; e++) {
            const float v = lg[t * 65 + e] + bias[e];
            if (v > v0) { v1 = v0; i1 = i0; v0 = v; i0 = e; }
            else if (v > v1) { v1 = v; i1 = e; }
        }
        const float e1 = expf(v1 - v0);   // v1 <= v0: stable
        const float sden = 1.f + e1;
        const int   g  = tok0 + t;
        out[2 * g + 0] = 1.f / sden;
        out[2 * g + 1] = e1 / sden;
        out[2 * NTOK + 2 * g + 0] = (float)i0;
        out[2 * NTOK + 2 * g + 1] = (float)i1;
    }
}

extern "C" void kernel_launch(void* const* d_in, const int* in_sizes, int n_in,
                              void* d_out, int out_size, void* d_ws, size_t ws_size,
                              hipStream_t stream) {
    const float* x    = (const float*)d_in[0];
    const float* W    = (const float*)d_in[1];
    const float* bias = (const float*)d_in[2];
    float*       out  = (float*)d_out;
    _Float16*    wsw  = (_Float16*)d_ws;

    if (ws_size >= (size_t)WSW_BYTES) {
        hipLaunchKernelGGL(wprep_kernel, dim3(64), dim3(256), 0, stream, (const float*)d_in[1], wsw);
        hipLaunchKernelGGL((gating_lds_kernel<true>), dim3(NBLK), dim3(256), 0, stream,
                           x, W, wsw, bias, out);
    } else {
        hipLaunchKernelGGL((gating_lds_kernel<false>), dim3(NBLK), dim3(256), 0, stream,
                           x, W, wsw, bias, out);
    }
}